// Round 7
// baseline (179.344 us; speedup 1.0000x reference)
//
#include <hip/hip_runtime.h>
#include <hip/hip_bf16.h>

#define HW   4096
#define HW4  1024
#define EPS  1e-5f
#define SM_SHIFT 20.0f   // constant-shift softmax: exp(s - SM_SHIFT); |s| << 20 by construction

typedef __attribute__((ext_vector_type(8))) short bf16x8;   // 8 bf16 (4 VGPRs)
typedef __attribute__((ext_vector_type(4))) float f32x4;    // MFMA C/D

__device__ __forceinline__ short f2bs(float f) {            // fp32 -> bf16 bits (RNE)
    union { float f; unsigned u; } v; v.f = f;
    unsigned r = v.u + 0x7FFFu + ((v.u >> 16) & 1u);
    return (short)(r >> 16);
}
__device__ __forceinline__ float bs2f(short s) {
    union { unsigned u; float f; } v; v.u = ((unsigned)(unsigned short)s) << 16;
    return v.f;
}
// XOR-swizzled LDS layouts (16B chunks permuted by row), row strides 64/128 shorts.
__device__ __forceinline__ int swz64(int r, int c)  { return (r << 6) + ((c ^ (r & 7))  << 3); }
__device__ __forceinline__ int swz128(int r, int c) { return (r << 7) + ((c ^ (r & 15)) << 3); }
// Padded 40-short (80B) rows: bank base = 20*r mod 32 -> full bank spread for 32-k rows.
__device__ __forceinline__ int p40(int r, int c)    { return r * 40 + c * 8; }

// ---------------------------------------------------------------------------
// Kernel 1: conv1x1+BN+ReLU branches 1-3, 2x2 maxpool fused in registers.
// Grid (32 ptile, 2 ocg, 8 bz) = 512 blocks -> 2 blocks/CU (was 1).
// Block = 96 oc x 128 p (one row pair). Wave owns 48 oc x 4 p-tiles laid out
// as {colhalf, colhalf+16} in both rows so vertical pooling stays in-register.
// ---------------------------------------------------------------------------
__global__ __launch_bounds__(256) void conv123pool(
    const float* __restrict__ x,
    const float* __restrict__ w1, const float* __restrict__ b1, const float* __restrict__ s1,
    const float* __restrict__ t1, const float* __restrict__ m1, const float* __restrict__ v1,
    const float* __restrict__ w2, const float* __restrict__ b2, const float* __restrict__ s2,
    const float* __restrict__ t2, const float* __restrict__ m2, const float* __restrict__ v2,
    const float* __restrict__ w3, const float* __restrict__ b3, const float* __restrict__ s3,
    const float* __restrict__ t3, const float* __restrict__ m3, const float* __restrict__ v3,
    short* __restrict__ gbuf, short* __restrict__ fbuf, short* __restrict__ hhbuf)
{
    __shared__ __align__(16) short Wl[96 * 64];    // [oc][k] swz64, 12KB
    __shared__ __align__(16) short Xl[128 * 64];   // [p][k]  swz64, 16KB
    __shared__ float alB[96], beB[96];

    const int t = threadIdx.x;
    const int lane = t & 63, wv = t >> 6;
    const int quad = lane >> 4, l16 = lane & 15;
    const int ptile = blockIdx.x;     // 0..31 (row pair)
    const int ocg   = blockIdx.y;     // 0..1
    const int bz    = blockIdx.z;
    const int pBase = ptile * 128;
    const int wcol  = (wv & 1) * 32;  // wave's column half
    const int woch  = (wv >> 1) * 48; // wave's oc half

    if (t < 96) {
        int j = ocg * 96 + t;
        float pb, ps, ptv, pm, pv;
        if (j < 32)      { pb = b1[j]; ps = s1[j]; ptv = t1[j]; pm = m1[j]; pv = v1[j]; }
        else if (j < 64) { int c = j - 32; pb = b2[c]; ps = s2[c]; ptv = t2[c]; pm = m2[c]; pv = v2[c]; }
        else             { int c = j - 64; pb = b3[c]; ps = s3[c]; ptv = t3[c]; pm = m3[c]; pv = v3[c]; }
        float al = ps * rsqrtf(pv + EPS);
        alB[t] = al; beB[t] = (pb - pm) * al + ptv;
    }

    const f32x4 fzero = {0.f, 0.f, 0.f, 0.f};
    f32x4 acc[3][4];                  // [oc-tile][p-tile]
    #pragma unroll
    for (int i = 0; i < 3; ++i)
        #pragma unroll
        for (int j = 0; j < 4; ++j) acc[i][j] = fzero;

    const int ptOff0 = wcol, ptOff1 = wcol + 16, ptOff2 = wcol + 64, ptOff3 = wcol + 80;
    const int xp  = t & 127, xk8 = t >> 7;

    for (int k0 = 0; k0 < 256; k0 += 64) {
        // stage W (96 oc x 64 k): 384 quarter-row tasks
        #pragma unroll
        for (int i = 0; i < 2; ++i) {
            int idx = t + i * 256;
            if (i == 0 || t < 128) {
                int oc = idx >> 2, kb = (idx & 3) * 16;
                int j = ocg * 96 + oc;
                const float* wp = (j < 32) ? (w1 + j * 256)
                                : (j < 64) ? (w2 + (j - 32) * 256)
                                           : (w3 + (j - 64) * 256);
                wp += k0 + kb;
                float4 a = *(const float4*)(wp);
                float4 b = *(const float4*)(wp + 4);
                float4 c = *(const float4*)(wp + 8);
                float4 d = *(const float4*)(wp + 12);
                bf16x8 lo, hi;
                lo[0]=f2bs(a.x); lo[1]=f2bs(a.y); lo[2]=f2bs(a.z); lo[3]=f2bs(a.w);
                lo[4]=f2bs(b.x); lo[5]=f2bs(b.y); lo[6]=f2bs(b.z); lo[7]=f2bs(b.w);
                hi[0]=f2bs(c.x); hi[1]=f2bs(c.y); hi[2]=f2bs(c.z); hi[3]=f2bs(c.w);
                hi[4]=f2bs(d.x); hi[5]=f2bs(d.y); hi[6]=f2bs(d.z); hi[7]=f2bs(d.w);
                *(bf16x8*)&Wl[swz64(oc, (kb >> 3))]     = lo;
                *(bf16x8*)&Wl[swz64(oc, (kb >> 3) + 1)] = hi;
            }
        }
        // stage X transposed: Xl[p][k], 32 k values per thread
        {
            const float* xp0 = x + ((size_t)bz * 256 + k0 + xk8 * 32) * HW + pBase + xp;
            float fv[32];
            #pragma unroll
            for (int i = 0; i < 32; ++i) fv[i] = xp0[(size_t)i * HW];
            #pragma unroll
            for (int c = 0; c < 4; ++c) {
                bf16x8 v;
                #pragma unroll
                for (int jj = 0; jj < 8; ++jj) v[jj] = f2bs(fv[c * 8 + jj]);
                *(bf16x8*)&Xl[swz64(xp, xk8 * 4 + c)] = v;
            }
        }
        __syncthreads();
        #pragma unroll
        for (int kk = 0; kk < 2; ++kk) {
            bf16x8 bfr[4];
            bfr[0] = *(const bf16x8*)&Xl[swz64(ptOff0 + l16, kk * 4 + quad)];
            bfr[1] = *(const bf16x8*)&Xl[swz64(ptOff1 + l16, kk * 4 + quad)];
            bfr[2] = *(const bf16x8*)&Xl[swz64(ptOff2 + l16, kk * 4 + quad)];
            bfr[3] = *(const bf16x8*)&Xl[swz64(ptOff3 + l16, kk * 4 + quad)];
            #pragma unroll
            for (int tt = 0; tt < 3; ++tt) {
                bf16x8 afr = *(const bf16x8*)&Wl[swz64(woch + tt * 16 + l16, kk * 4 + quad)];
                #pragma unroll
                for (int pt = 0; pt < 4; ++pt)
                    acc[tt][pt] = __builtin_amdgcn_mfma_f32_16x16x32_bf16(afr, bfr[pt], acc[tt][pt], 0, 0, 0);
            }
        }
        __syncthreads();
    }

    // epilogue: BN+ReLU; g stores unpooled, f/hh pool 2x2 (vert pt c vs c+2, horz shfl 1)
    #pragma unroll
    for (int tt = 0; tt < 3; ++tt) {
        #pragma unroll
        for (int r = 0; r < 4; ++r) {
            int ocl = woch + tt * 16 + quad * 4 + r;
            int j = ocg * 96 + ocl;
            float al = alB[ocl], be = beB[ocl];
            float y[4];
            y[0] = fmaxf(acc[tt][0][r] * al + be, 0.f);
            y[1] = fmaxf(acc[tt][1][r] * al + be, 0.f);
            y[2] = fmaxf(acc[tt][2][r] * al + be, 0.f);
            y[3] = fmaxf(acc[tt][3][r] * al + be, 0.f);
            if (j >= 32 && j < 64) {        // g: store unpooled
                size_t base = ((size_t)bz * 32 + (j - 32)) * HW + pBase;
                gbuf[base + ptOff0 + l16] = f2bs(y[0]);
                gbuf[base + ptOff1 + l16] = f2bs(y[1]);
                gbuf[base + ptOff2 + l16] = f2bs(y[2]);
                gbuf[base + ptOff3 + l16] = f2bs(y[3]);
            } else {                        // f / hh: 2x2 maxpool
                #pragma unroll
                for (int c = 0; c < 2; ++c) {
                    float v  = fmaxf(y[c], y[c + 2]);
                    float po = fmaxf(v, __shfl_xor(v, 1));
                    if ((l16 & 1) == 0) {
                        int col = wcol + c * 16 + l16;          // 0..63 within row
                        int n = ptile * 32 + (col >> 1);
                        if (j < 32) fbuf[((size_t)bz * 32 + j) * HW4 + n] = f2bs(po);
                        else        hhbuf[((size_t)bz * 128 + (j - 64)) * HW4 + n] = f2bs(po);
                    }
                }
            }
        }
    }
}

// ---------------------------------------------------------------------------
// Kernel 2: attention partial, n-split x c-split. Grid (64 mtile, 4, 8) =
// 2048 blocks; blockIdx.y = np + 2*cp. LDS 26.6KB -> 5-6 blocks/CU.
// s-compute duplicated across cp (cheap); o-compute split (cp's 64 channels).
// Constant-shift softmax keeps partials linear (merge by addition).
// ---------------------------------------------------------------------------
__global__ __launch_bounds__(256, 5) void attn_partial(
    const short* __restrict__ gbuf,
    const short* __restrict__ fbuf,
    const short* __restrict__ hhbuf,
    short* __restrict__ opart,    // [8][2][4096][128] bf16
    float* __restrict__ Zbuf)     // [8][2][4096] fp32
{
    __shared__ __align__(16) short smem[13312];    // 26624 B
    short* gTl = smem;            // [64m][32k]  p40,   2560 shorts
    short* fTl = smem + 2560;     // [64n][32k]  p40,   2560
    short* sTl = smem + 5120;     // [64m][64n]  swz64, 4096 (beta^T, unnormalized)
    short* hhl = smem + 9216;     // [64c][64n]  swz64, 4096

    const int t = threadIdx.x;
    const int lane = t & 63, wv = t >> 6;
    const int quad = lane >> 4, l16 = lane & 15;
    const int bz = blockIdx.z;
    const int np = blockIdx.y & 1;
    const int cp = blockIdx.y >> 1;
    const int m0 = blockIdx.x * 64;
    const int ms = wv * 16;
    const f32x4 fzero = {0.f, 0.f, 0.f, 0.f};

    // stage g^T once: gTl[m][k]
    {
        int mm = t & 63, k8 = t >> 6;
        bf16x8 v;
        #pragma unroll
        for (int j = 0; j < 8; ++j)
            v[j] = gbuf[((size_t)bz * 32 + k8 * 8 + j) * HW + m0 + mm];
        *(bf16x8*)&gTl[p40(mm, k8)] = v;
    }
    __syncthreads();
    bf16x8 bg = *(const bf16x8*)&gTl[p40(ms + l16, quad)];   // loop-invariant B-frag

    const int fnn = t & 63, fk8 = t >> 6;
    const int hrow = t >> 3, hnc = t & 7;
    const short* fB = fbuf + (size_t)bz * 32 * HW4;
    const short* hB = hhbuf + ((size_t)bz * 128 + cp * 64) * HW4;

    float psum = 0.f;
    f32x4 oacc[4];
    #pragma unroll
    for (int i = 0; i < 4; ++i) oacc[i] = fzero;

    const int nbase = np * 512;
    for (int n0 = nbase; n0 < nbase + 512; n0 += 64) {
        __syncthreads();   // prior-iter readers of fTl/hhl done
        {   // stage f^T: fTl[n][k]
            bf16x8 v;
            #pragma unroll
            for (int j = 0; j < 8; ++j)
                v[j] = fB[(fk8 * 8 + j) * HW4 + n0 + fnn];
            *(bf16x8*)&fTl[p40(fnn, fk8)] = v;
        }
        {   // stage hh (cp's 64 channels): hhl[c][n]
            #pragma unroll
            for (int i = 0; i < 2; ++i)
                *(bf16x8*)&hhl[swz64(i * 32 + hrow, hnc)] =
                    *(const bf16x8*)(hB + (size_t)(i * 32 + hrow) * HW4 + n0 + hnc * 8);
        }
        __syncthreads();

        // s-phase: s[n][m] for wave's 16-m strip
        f32x4 sacc[4];
        #pragma unroll
        for (int nt = 0; nt < 4; ++nt) {
            bf16x8 af = *(const bf16x8*)&fTl[p40(nt * 16 + l16, quad)];
            sacc[nt] = __builtin_amdgcn_mfma_f32_16x16x32_bf16(af, bg, fzero, 0, 0, 0);
        }

        // exp(s - C), per-lane partial sum (no cross-lane ops in loop)
        #pragma unroll
        for (int nt = 0; nt < 4; ++nt) {
            short4 ev;
            #pragma unroll
            for (int r = 0; r < 4; ++r) {
                float e = __expf(sacc[nt][r] - SM_SHIFT);
                psum += e;
                ((short*)&ev)[r] = f2bs(e);
            }
            int chunk = nt * 2 + (quad >> 1);
            *(short4*)&sTl[swz64(ms + l16, chunk) + (quad & 1) * 4] = ev;   // beta^T[m][n]
        }

        // o-phase: o[c][m] += hh[c][n] * beta[n][m]; wave reads own sTl rows only
        #pragma unroll
        for (int kk = 0; kk < 2; ++kk) {
            bf16x8 bs = *(const bf16x8*)&sTl[swz64(ms + l16, kk * 4 + quad)];
            #pragma unroll
            for (int ct = 0; ct < 4; ++ct) {
                bf16x8 ah = *(const bf16x8*)&hhl[swz64(ct * 16 + l16, kk * 4 + quad)];
                oacc[ct] = __builtin_amdgcn_mfma_f32_16x16x32_bf16(ah, bs, oacc[ct], 0, 0, 0);
            }
        }
    }

    // Z partial (duplicated across cp -> only cp 0 writes)
    psum += __shfl_xor(psum, 16);
    psum += __shfl_xor(psum, 32);
    int m = m0 + ms + l16;
    if (cp == 0 && quad == 0)
        Zbuf[((size_t)bz * 2 + np) * HW + m] = psum;

    // store unnormalized o_part[b][np][m][cp*64 + c]
    #pragma unroll
    for (int ct = 0; ct < 4; ++ct) {
        short4 ov;
        #pragma unroll
        for (int r = 0; r < 4; ++r) ((short*)&ov)[r] = f2bs(oacc[ct][r]);
        *(short4*)(opart + (((size_t)bz * 2 + np) * HW + m) * 128 + cp * 64 + ct * 16 + quad * 4) = ov;
    }
}

// ---------------------------------------------------------------------------
// Kernel 3: merge n-partials + normalize + conv4 + BN + gamma*y + x residual.
// Grid (64 mtile, 8 bz). HBM-ish bound (~100MB traffic).
// ---------------------------------------------------------------------------
__global__ __launch_bounds__(256) void conv4_merge(
    const short* __restrict__ opart,
    const float* __restrict__ Zbuf,
    const float* __restrict__ x,
    const float* __restrict__ w4, const float* __restrict__ b4, const float* __restrict__ s4,
    const float* __restrict__ t4, const float* __restrict__ m4, const float* __restrict__ v4,
    const float* __restrict__ gamma, float* __restrict__ out)
{
    __shared__ __align__(16) short smem[24576];    // 48KB
    __shared__ float alB4[256], beB4[256];
    short* o_l = smem;            // [64m][128c] swz128, 8192 shorts
    short* Wl4 = smem + 8192;     // [256oc][64k] swz64, 16384 shorts

    const int t = threadIdx.x;
    const int lane = t & 63, wv = t >> 6;
    const int quad = lane >> 4, l16 = lane & 15;
    const int bz = blockIdx.y;
    const int m0 = blockIdx.x * 64;
    const f32x4 fzero = {0.f, 0.f, 0.f, 0.f};

    {   // conv4 BN constants
        float al = s4[t] * rsqrtf(v4[t] + EPS);
        alB4[t] = al; beB4[t] = (b4[t] - m4[t]) * al + t4[t];
    }

    // merge partials -> normalized o_l[m][c]
    {
        int m = t >> 2, cb = (t & 3) * 32;
        size_t mi = (size_t)m0 + m;
        const short* p0 = opart + (((size_t)bz * 2 + 0) * HW + mi) * 128 + cb;
        const short* p1 = opart + (((size_t)bz * 2 + 1) * HW + mi) * 128 + cb;
        float z = Zbuf[((size_t)bz * 2 + 0) * HW + mi] + Zbuf[((size_t)bz * 2 + 1) * HW + mi];
        float inv = 1.0f / z;
        #pragma unroll
        for (int seg = 0; seg < 4; ++seg) {
            bf16x8 a = *(const bf16x8*)(p0 + seg * 8);
            bf16x8 b = *(const bf16x8*)(p1 + seg * 8);
            bf16x8 o;
            #pragma unroll
            for (int j = 0; j < 8; ++j)
                o[j] = f2bs((bs2f(a[j]) + bs2f(b[j])) * inv);
            *(bf16x8*)&o_l[swz128(m, (cb >> 3) + seg)] = o;
        }
    }

    // conv4: out[oc][m] = W4(256x128) . o(128x64m)
    f32x4 acc4[4][4];
    #pragma unroll
    for (int i = 0; i < 4; ++i)
        #pragma unroll
        for (int j = 0; j < 4; ++j) acc4[i][j] = fzero;

    for (int c0 = 0; c0 < 128; c0 += 64) {
        #pragma unroll
        for (int i = 0; i < 4; ++i) {
            int oc = i * 64 + (t >> 2);
            int kb = (t & 3) * 16;
            const float* wp = w4 + oc * 128 + c0 + kb;
            float4 a = *(const float4*)(wp);
            float4 b = *(const float4*)(wp + 4);
            float4 c = *(const float4*)(wp + 8);
            float4 d = *(const float4*)(wp + 12);
            bf16x8 lo, hi;
            lo[0]=f2bs(a.x); lo[1]=f2bs(a.y); lo[2]=f2bs(a.z); lo[3]=f2bs(a.w);
            lo[4]=f2bs(b.x); lo[5]=f2bs(b.y); lo[6]=f2bs(b.z); lo[7]=f2bs(b.w);
            hi[0]=f2bs(c.x); hi[1]=f2bs(c.y); hi[2]=f2bs(c.z); hi[3]=f2bs(c.w);
            hi[4]=f2bs(d.x); hi[5]=f2bs(d.y); hi[6]=f2bs(d.z); hi[7]=f2bs(d.w);
            *(bf16x8*)&Wl4[swz64(oc, (kb >> 3))]     = lo;
            *(bf16x8*)&Wl4[swz64(oc, (kb >> 3) + 1)] = hi;
        }
        __syncthreads();   // o_l + Wl4 visible
        #pragma unroll
        for (int kk = 0; kk < 2; ++kk) {
            bf16x8 bfr[4];
            #pragma unroll
            for (int mt = 0; mt < 4; ++mt)
                bfr[mt] = *(const bf16x8*)&o_l[swz128(mt * 16 + l16, (c0 >> 3) + kk * 4 + quad)];
            #pragma unroll
            for (int ot = 0; ot < 4; ++ot) {
                bf16x8 afr = *(const bf16x8*)&Wl4[swz64(wv * 64 + ot * 16 + l16, kk * 4 + quad)];
                #pragma unroll
                for (int mt = 0; mt < 4; ++mt)
                    acc4[ot][mt] = __builtin_amdgcn_mfma_f32_16x16x32_bf16(afr, bfr[mt], acc4[ot][mt], 0, 0, 0);
            }
        }
        __syncthreads();
    }

    float gm = gamma[0];
    #pragma unroll
    for (int ot = 0; ot < 4; ++ot) {
        #pragma unroll
        for (int r = 0; r < 4; ++r) {
            int oc = wv * 64 + ot * 16 + quad * 4 + r;
            float al = alB4[oc], be = beB4[oc];
            #pragma unroll
            for (int mt = 0; mt < 4; ++mt) {
                int p = m0 + mt * 16 + l16;
                float y  = acc4[ot][mt][r] * al + be;
                float xo = x[((size_t)bz * 256 + oc) * HW + p];
                out[((size_t)bz * 256 + oc) * HW + p] = gm * y + xo;
            }
        }
    }
}

extern "C" void kernel_launch(void* const* d_in, const int* in_sizes, int n_in,
                              void* d_out, int out_size, void* d_ws, size_t ws_size,
                              hipStream_t stream)
{
    const float* x  = (const float*)d_in[0];
    const float* w1 = (const float*)d_in[1];
    const float* b1 = (const float*)d_in[2];
    const float* s1 = (const float*)d_in[3];
    const float* t1 = (const float*)d_in[4];
    const float* m1 = (const float*)d_in[5];
    const float* v1 = (const float*)d_in[6];
    const float* w2 = (const float*)d_in[7];
    const float* b2 = (const float*)d_in[8];
    const float* s2 = (const float*)d_in[9];
    const float* t2 = (const float*)d_in[10];
    const float* m2 = (const float*)d_in[11];
    const float* v2 = (const float*)d_in[12];
    const float* w3 = (const float*)d_in[13];
    const float* b3 = (const float*)d_in[14];
    const float* s3 = (const float*)d_in[15];
    const float* t3 = (const float*)d_in[16];
    const float* m3 = (const float*)d_in[17];
    const float* v3 = (const float*)d_in[18];
    const float* w4 = (const float*)d_in[19];
    const float* b4 = (const float*)d_in[20];
    const float* s4 = (const float*)d_in[21];
    const float* t4 = (const float*)d_in[22];
    const float* m4 = (const float*)d_in[23];
    const float* v4 = (const float*)d_in[24];
    const float* gm = (const float*)d_in[25];
    float* out = (float*)d_out;

    short* gbuf  = (short*)d_ws;                     // 8*32*4096 bf16 (2 MB)
    short* fbuf  = gbuf  + (size_t)8 * 32 * 4096;    // 8*32*1024  (0.5 MB)
    short* hhbuf = fbuf  + (size_t)8 * 32 * 1024;    // 8*128*1024 (2 MB)
    short* opart = hhbuf + (size_t)8 * 128 * 1024;   // 8*2*4096*128 (16.8 MB)
    float* Zbuf  = (float*)(opart + (size_t)8 * 2 * 4096 * 128);  // 8*2*4096 fp32

    conv123pool<<<dim3(32, 2, 8), 256, 0, stream>>>(
        x, w1, b1, s1, t1, m1, v1, w2, b2, s2, t2, m2, v2, w3, b3, s3, t3, m3, v3,
        gbuf, fbuf, hhbuf);
    attn_partial<<<dim3(64, 4, 8), 256, 0, stream>>>(
        gbuf, fbuf, hhbuf, opart, Zbuf);
    conv4_merge<<<dim3(64, 8), 256, 0, stream>>>(
        opart, Zbuf, x, w4, b4, s4, t4, m4, v4, gm, out);
}

// Round 8
// 172.310 us; speedup vs baseline: 1.0408x; 1.0408x over previous
//
#include <hip/hip_runtime.h>
#include <hip/hip_bf16.h>

#define HW   4096
#define HW4  1024
#define EPS  1e-5f
#define SM_SHIFT 20.0f   // constant-shift softmax: exp(s - SM_SHIFT); |s| << 20 by construction

typedef __attribute__((ext_vector_type(8))) short bf16x8;   // 8 bf16 (4 VGPRs)
typedef __attribute__((ext_vector_type(4))) float f32x4;    // MFMA C/D

__device__ __forceinline__ short f2bs(float f) {            // fp32 -> bf16 bits (RNE)
    union { float f; unsigned u; } v; v.f = f;
    unsigned r = v.u + 0x7FFFu + ((v.u >> 16) & 1u);
    return (short)(r >> 16);
}
// XOR-swizzled LDS layouts (16B chunks permuted by row), row strides 64/128 shorts.
__device__ __forceinline__ int swz64(int r, int c)  { return (r << 6) + ((c ^ (r & 7))  << 3); }
__device__ __forceinline__ int swz128(int r, int c) { return (r << 7) + ((c ^ (r & 15)) << 3); }
// Padded 40-short (80B) rows: bank base = 20*r mod 32 -> full bank spread for 32-k rows.
__device__ __forceinline__ int p40(int r, int c)    { return r * 40 + c * 8; }

// ---------------------------------------------------------------------------
// Kernel 1: conv1x1+BN+ReLU branches 1-3, 2x2 maxpool fused in registers.
// Grid (32 ptile, 2 ocg, 8 bz) = 512 blocks -> 2 blocks/CU.
// ---------------------------------------------------------------------------
__global__ __launch_bounds__(256) void conv123pool(
    const float* __restrict__ x,
    const float* __restrict__ w1, const float* __restrict__ b1, const float* __restrict__ s1,
    const float* __restrict__ t1, const float* __restrict__ m1, const float* __restrict__ v1,
    const float* __restrict__ w2, const float* __restrict__ b2, const float* __restrict__ s2,
    const float* __restrict__ t2, const float* __restrict__ m2, const float* __restrict__ v2,
    const float* __restrict__ w3, const float* __restrict__ b3, const float* __restrict__ s3,
    const float* __restrict__ t3, const float* __restrict__ m3, const float* __restrict__ v3,
    short* __restrict__ gbuf, short* __restrict__ fbuf, short* __restrict__ hhbuf)
{
    __shared__ __align__(16) short Wl[96 * 64];    // [oc][k] swz64, 12KB
    __shared__ __align__(16) short Xl[128 * 64];   // [p][k]  swz64, 16KB
    __shared__ float alB[96], beB[96];

    const int t = threadIdx.x;
    const int lane = t & 63, wv = t >> 6;
    const int quad = lane >> 4, l16 = lane & 15;
    const int ptile = blockIdx.x;     // 0..31 (row pair)
    const int ocg   = blockIdx.y;     // 0..1
    const int bz    = blockIdx.z;
    const int pBase = ptile * 128;
    const int wcol  = (wv & 1) * 32;  // wave's column half
    const int woch  = (wv >> 1) * 48; // wave's oc half

    if (t < 96) {
        int j = ocg * 96 + t;
        float pb, ps, ptv, pm, pv;
        if (j < 32)      { pb = b1[j]; ps = s1[j]; ptv = t1[j]; pm = m1[j]; pv = v1[j]; }
        else if (j < 64) { int c = j - 32; pb = b2[c]; ps = s2[c]; ptv = t2[c]; pm = m2[c]; pv = v2[c]; }
        else             { int c = j - 64; pb = b3[c]; ps = s3[c]; ptv = t3[c]; pm = m3[c]; pv = v3[c]; }
        float al = ps * rsqrtf(pv + EPS);
        alB[t] = al; beB[t] = (pb - pm) * al + ptv;
    }

    const f32x4 fzero = {0.f, 0.f, 0.f, 0.f};
    f32x4 acc[3][4];                  // [oc-tile][p-tile]
    #pragma unroll
    for (int i = 0; i < 3; ++i)
        #pragma unroll
        for (int j = 0; j < 4; ++j) acc[i][j] = fzero;

    const int ptOff0 = wcol, ptOff1 = wcol + 16, ptOff2 = wcol + 64, ptOff3 = wcol + 80;
    const int xp  = t & 127, xk8 = t >> 7;

    for (int k0 = 0; k0 < 256; k0 += 64) {
        #pragma unroll
        for (int i = 0; i < 2; ++i) {
            int idx = t + i * 256;
            if (i == 0 || t < 128) {
                int oc = idx >> 2, kb = (idx & 3) * 16;
                int j = ocg * 96 + oc;
                const float* wp = (j < 32) ? (w1 + j * 256)
                                : (j < 64) ? (w2 + (j - 32) * 256)
                                           : (w3 + (j - 64) * 256);
                wp += k0 + kb;
                float4 a = *(const float4*)(wp);
                float4 b = *(const float4*)(wp + 4);
                float4 c = *(const float4*)(wp + 8);
                float4 d = *(const float4*)(wp + 12);
                bf16x8 lo, hi;
                lo[0]=f2bs(a.x); lo[1]=f2bs(a.y); lo[2]=f2bs(a.z); lo[3]=f2bs(a.w);
                lo[4]=f2bs(b.x); lo[5]=f2bs(b.y); lo[6]=f2bs(b.z); lo[7]=f2bs(b.w);
                hi[0]=f2bs(c.x); hi[1]=f2bs(c.y); hi[2]=f2bs(c.z); hi[3]=f2bs(c.w);
                hi[4]=f2bs(d.x); hi[5]=f2bs(d.y); hi[6]=f2bs(d.z); hi[7]=f2bs(d.w);
                *(bf16x8*)&Wl[swz64(oc, (kb >> 3))]     = lo;
                *(bf16x8*)&Wl[swz64(oc, (kb >> 3) + 1)] = hi;
            }
        }
        {
            const float* xp0 = x + ((size_t)bz * 256 + k0 + xk8 * 32) * HW + pBase + xp;
            float fv[32];
            #pragma unroll
            for (int i = 0; i < 32; ++i) fv[i] = xp0[(size_t)i * HW];
            #pragma unroll
            for (int c = 0; c < 4; ++c) {
                bf16x8 v;
                #pragma unroll
                for (int jj = 0; jj < 8; ++jj) v[jj] = f2bs(fv[c * 8 + jj]);
                *(bf16x8*)&Xl[swz64(xp, xk8 * 4 + c)] = v;
            }
        }
        __syncthreads();
        #pragma unroll
        for (int kk = 0; kk < 2; ++kk) {
            bf16x8 bfr[4];
            bfr[0] = *(const bf16x8*)&Xl[swz64(ptOff0 + l16, kk * 4 + quad)];
            bfr[1] = *(const bf16x8*)&Xl[swz64(ptOff1 + l16, kk * 4 + quad)];
            bfr[2] = *(const bf16x8*)&Xl[swz64(ptOff2 + l16, kk * 4 + quad)];
            bfr[3] = *(const bf16x8*)&Xl[swz64(ptOff3 + l16, kk * 4 + quad)];
            #pragma unroll
            for (int tt = 0; tt < 3; ++tt) {
                bf16x8 afr = *(const bf16x8*)&Wl[swz64(woch + tt * 16 + l16, kk * 4 + quad)];
                #pragma unroll
                for (int pt = 0; pt < 4; ++pt)
                    acc[tt][pt] = __builtin_amdgcn_mfma_f32_16x16x32_bf16(afr, bfr[pt], acc[tt][pt], 0, 0, 0);
            }
        }
        __syncthreads();
    }

    #pragma unroll
    for (int tt = 0; tt < 3; ++tt) {
        #pragma unroll
        for (int r = 0; r < 4; ++r) {
            int ocl = woch + tt * 16 + quad * 4 + r;
            int j = ocg * 96 + ocl;
            float al = alB[ocl], be = beB[ocl];
            float y[4];
            y[0] = fmaxf(acc[tt][0][r] * al + be, 0.f);
            y[1] = fmaxf(acc[tt][1][r] * al + be, 0.f);
            y[2] = fmaxf(acc[tt][2][r] * al + be, 0.f);
            y[3] = fmaxf(acc[tt][3][r] * al + be, 0.f);
            if (j >= 32 && j < 64) {        // g: store unpooled
                size_t base = ((size_t)bz * 32 + (j - 32)) * HW + pBase;
                gbuf[base + ptOff0 + l16] = f2bs(y[0]);
                gbuf[base + ptOff1 + l16] = f2bs(y[1]);
                gbuf[base + ptOff2 + l16] = f2bs(y[2]);
                gbuf[base + ptOff3 + l16] = f2bs(y[3]);
            } else {                        // f / hh: 2x2 maxpool
                #pragma unroll
                for (int c = 0; c < 2; ++c) {
                    float v  = fmaxf(y[c], y[c + 2]);
                    float po = fmaxf(v, __shfl_xor(v, 1));
                    if ((l16 & 1) == 0) {
                        int col = wcol + c * 16 + l16;
                        int n = ptile * 32 + (col >> 1);
                        if (j < 32) fbuf[((size_t)bz * 32 + j) * HW4 + n] = f2bs(po);
                        else        hhbuf[((size_t)bz * 128 + (j - 64)) * HW4 + n] = f2bs(po);
                    }
                }
            }
        }
    }
}

// ---------------------------------------------------------------------------
// Kernel 2: fused attention (constant-shift softmax) + conv4 + BN + residual.
// Grid (64 mtile, 8 bz) = 512 blocks. LDS peak 36.9KB + 2KB -> 4 blocks/CU.
// No flash max/rescale: exp(s-20) is linear in n; Z reduced in-register at
// loop exit. Phase 2 stages conv4 W in 32-k chunks to fit the LDS budget.
// ---------------------------------------------------------------------------
__global__ __launch_bounds__(256, 4) void attn_conv4(
    const short* __restrict__ gbuf,
    const short* __restrict__ fbuf,
    const short* __restrict__ hhbuf,
    const float* __restrict__ x,
    const float* __restrict__ w4, const float* __restrict__ b4, const float* __restrict__ s4,
    const float* __restrict__ t4, const float* __restrict__ m4, const float* __restrict__ v4,
    const float* __restrict__ gamma, float* __restrict__ out)
{
    __shared__ __align__(16) short smem[18432];    // 36864 B
    __shared__ float alB4[256], beB4[256];
    short* gTl = smem;            // [64m][32k]  p40,   2560 shorts (phase 1)
    short* fTl = smem + 2560;     // [64n][32k]  p40,   2560
    short* sTl = smem + 5120;     // [64m][64n]  swz64, 4096 (beta^T, unnormalized)
    short* hhl = smem + 9216;     // [128c][64n] swz64, 8192
    short* o_l = smem;            // [64m][128c] swz128, 8192 (phase 2)
    short* Wl4 = smem + 8192;     // [256oc][32k] p40, 10240 (phase 2)

    const int t = threadIdx.x;
    const int lane = t & 63, wv = t >> 6;
    const int quad = lane >> 4, l16 = lane & 15;
    const int bz = blockIdx.y;
    const int m0 = blockIdx.x * 64;
    const int ms = wv * 16;
    const f32x4 fzero = {0.f, 0.f, 0.f, 0.f};

    {   // conv4 BN constants
        float al = s4[t] * rsqrtf(v4[t] + EPS);
        alB4[t] = al; beB4[t] = (b4[t] - m4[t]) * al + t4[t];
    }

    // stage g^T once: gTl[m][k]
    {
        int mm = t & 63, k8 = t >> 6;
        bf16x8 v;
        #pragma unroll
        for (int j = 0; j < 8; ++j)
            v[j] = gbuf[((size_t)bz * 32 + k8 * 8 + j) * HW + m0 + mm];
        *(bf16x8*)&gTl[p40(mm, k8)] = v;
    }
    __syncthreads();
    bf16x8 bg = *(const bf16x8*)&gTl[p40(ms + l16, quad)];   // loop-invariant B-frag

    const int fnn = t & 63, fk8 = t >> 6;
    const int hrow = t >> 3, hnc = t & 7;
    const short* fB = fbuf + (size_t)bz * 32 * HW4;
    const short* hB = hhbuf + (size_t)bz * 128 * HW4;

    float psum = 0.f;
    f32x4 oacc[8];
    #pragma unroll
    for (int i = 0; i < 8; ++i) oacc[i] = fzero;

    for (int n0 = 0; n0 < 1024; n0 += 64) {
        __syncthreads();   // prior-iter readers of fTl/hhl done
        {   // stage f^T: fTl[n][k]
            bf16x8 v;
            #pragma unroll
            for (int j = 0; j < 8; ++j)
                v[j] = fB[(fk8 * 8 + j) * HW4 + n0 + fnn];
            *(bf16x8*)&fTl[p40(fnn, fk8)] = v;
        }
        {   // stage hh: hhl[c][n]
            #pragma unroll
            for (int i = 0; i < 4; ++i)
                *(bf16x8*)&hhl[swz64(i * 32 + hrow, hnc)] =
                    *(const bf16x8*)(hB + (size_t)(i * 32 + hrow) * HW4 + n0 + hnc * 8);
        }
        __syncthreads();

        // s-phase: s[n][m] for wave's 16-m strip
        f32x4 sacc[4];
        #pragma unroll
        for (int nt = 0; nt < 4; ++nt) {
            bf16x8 af = *(const bf16x8*)&fTl[p40(nt * 16 + l16, quad)];
            sacc[nt] = __builtin_amdgcn_mfma_f32_16x16x32_bf16(af, bg, fzero, 0, 0, 0);
        }

        // exp(s - C), per-lane partial sum; no cross-lane ops, no rescale
        #pragma unroll
        for (int nt = 0; nt < 4; ++nt) {
            short4 ev;
            #pragma unroll
            for (int r = 0; r < 4; ++r) {
                float e = __expf(sacc[nt][r] - SM_SHIFT);
                psum += e;
                ((short*)&ev)[r] = f2bs(e);
            }
            int chunk = nt * 2 + (quad >> 1);
            *(short4*)&sTl[swz64(ms + l16, chunk) + (quad & 1) * 4] = ev;   // beta^T[m][n]
        }

        // o-phase: o[c][m] += hh[c][n] * beta[n][m]; wave reads own sTl rows only
        #pragma unroll
        for (int kk = 0; kk < 2; ++kk) {
            bf16x8 bs = *(const bf16x8*)&sTl[swz64(ms + l16, kk * 4 + quad)];
            #pragma unroll
            for (int ct = 0; ct < 8; ++ct) {
                bf16x8 ah = *(const bf16x8*)&hhl[swz64(ct * 16 + l16, kk * 4 + quad)];
                oacc[ct] = __builtin_amdgcn_mfma_f32_16x16x32_bf16(ah, bs, oacc[ct], 0, 0, 0);
            }
        }
    }
    __syncthreads();   // all attn LDS reads complete

    // normalize in-register: Z for m = ms+l16 (reduce psum across quads)
    psum += __shfl_xor(psum, 16);
    psum += __shfl_xor(psum, 32);
    {
        float inv = 1.0f / psum;
        int m = ms + l16;
        #pragma unroll
        for (int ct = 0; ct < 8; ++ct) {
            short4 ov;
            #pragma unroll
            for (int r = 0; r < 4; ++r) ((short*)&ov)[r] = f2bs(oacc[ct][r] * inv);
            *(short4*)&o_l[swz128(m, ct * 2 + (quad >> 1)) + (quad & 1) * 4] = ov;
        }
    }

    // conv4: out[oc][m] = W4(256x128) . o(128x64m); W staged in 32-k chunks
    f32x4 acc4[4][4];
    #pragma unroll
    for (int i = 0; i < 4; ++i)
        #pragma unroll
        for (int j = 0; j < 4; ++j) acc4[i][j] = fzero;

    #pragma unroll
    for (int k0 = 0; k0 < 128; k0 += 32) {
        __syncthreads();   // o_l ready (first iter) / prior MFMA reads done
        {   // stage Wl4[oc][32k]: thread t -> oc row t
            const float* wp = w4 + t * 128 + k0;
            #pragma unroll
            for (int c = 0; c < 4; ++c) {
                float4 a = *(const float4*)(wp + c * 8);
                float4 b = *(const float4*)(wp + c * 8 + 4);
                bf16x8 v;
                v[0]=f2bs(a.x); v[1]=f2bs(a.y); v[2]=f2bs(a.z); v[3]=f2bs(a.w);
                v[4]=f2bs(b.x); v[5]=f2bs(b.y); v[6]=f2bs(b.z); v[7]=f2bs(b.w);
                *(bf16x8*)&Wl4[p40(t, c)] = v;
            }
        }
        __syncthreads();
        bf16x8 bfr[4];
        #pragma unroll
        for (int mt = 0; mt < 4; ++mt)
            bfr[mt] = *(const bf16x8*)&o_l[swz128(mt * 16 + l16, (k0 >> 3) + quad)];
        #pragma unroll
        for (int ot = 0; ot < 4; ++ot) {
            bf16x8 afr = *(const bf16x8*)&Wl4[p40(wv * 64 + ot * 16 + l16, quad)];
            #pragma unroll
            for (int mt = 0; mt < 4; ++mt)
                acc4[ot][mt] = __builtin_amdgcn_mfma_f32_16x16x32_bf16(afr, bfr[mt], acc4[ot][mt], 0, 0, 0);
        }
    }

    float gm = gamma[0];
    #pragma unroll
    for (int ot = 0; ot < 4; ++ot) {
        #pragma unroll
        for (int r = 0; r < 4; ++r) {
            int oc = wv * 64 + ot * 16 + quad * 4 + r;
            float al = alB4[oc], be = beB4[oc];
            #pragma unroll
            for (int mt = 0; mt < 4; ++mt) {
                int p = m0 + mt * 16 + l16;
                float y  = acc4[ot][mt][r] * al + be;
                float xo = x[((size_t)bz * 256 + oc) * HW + p];
                out[((size_t)bz * 256 + oc) * HW + p] = gm * y + xo;
            }
        }
    }
}

extern "C" void kernel_launch(void* const* d_in, const int* in_sizes, int n_in,
                              void* d_out, int out_size, void* d_ws, size_t ws_size,
                              hipStream_t stream)
{
    const float* x  = (const float*)d_in[0];
    const float* w1 = (const float*)d_in[1];
    const float* b1 = (const float*)d_in[2];
    const float* s1 = (const float*)d_in[3];
    const float* t1 = (const float*)d_in[4];
    const float* m1 = (const float*)d_in[5];
    const float* v1 = (const float*)d_in[6];
    const float* w2 = (const float*)d_in[7];
    const float* b2 = (const float*)d_in[8];
    const float* s2 = (const float*)d_in[9];
    const float* t2 = (const float*)d_in[10];
    const float* m2 = (const float*)d_in[11];
    const float* v2 = (const float*)d_in[12];
    const float* w3 = (const float*)d_in[13];
    const float* b3 = (const float*)d_in[14];
    const float* s3 = (const float*)d_in[15];
    const float* t3 = (const float*)d_in[16];
    const float* m3 = (const float*)d_in[17];
    const float* v3 = (const float*)d_in[18];
    const float* w4 = (const float*)d_in[19];
    const float* b4 = (const float*)d_in[20];
    const float* s4 = (const float*)d_in[21];
    const float* t4 = (const float*)d_in[22];
    const float* m4 = (const float*)d_in[23];
    const float* v4 = (const float*)d_in[24];
    const float* gm = (const float*)d_in[25];
    float* out = (float*)d_out;

    short* gbuf  = (short*)d_ws;                     // 8*32*4096 bf16 (2 MB)
    short* fbuf  = gbuf  + (size_t)8 * 32 * 4096;    // 8*32*1024  (0.5 MB)
    short* hhbuf = fbuf  + (size_t)8 * 32 * 1024;    // 8*128*1024 (2 MB)

    conv123pool<<<dim3(32, 2, 8), 256, 0, stream>>>(
        x, w1, b1, s1, t1, m1, v1, w2, b2, s2, t2, m2, v2, w3, b3, s3, t3, m3, v3,
        gbuf, fbuf, hhbuf);
    attn_conv4<<<dim3(64, 8), 256, 0, stream>>>(
        gbuf, fbuf, hhbuf, x, w4, b4, s4, t4, m4, v4, gm, out);
}